// Round 7
// baseline (16.290 us; speedup 1.0000x reference)
//
#include <hip/hip_runtime.h>
#include <math.h>

#define TLEN   256
#define NFEAT  16
#define NBATCH 32
#define BETA   2.5f
#define EPSW   1e-12f
#define W_BI   0.05f
#define W_L2   0.01f
#define L2E    1.4426950408889634f
#define LB     (BETA * L2E)

#if __has_builtin(__builtin_amdgcn_exp2f)
#define EXP2(x) __builtin_amdgcn_exp2f(x)
#else
#define EXP2(x) exp2f(x)
#endif

__device__ inline float sigm(float v) { return 1.f / (1.f + __expf(-v)); }
__device__ inline float clamp01(float v) { return fminf(fmaxf(v, 0.f), 1.f); }
__device__ inline float rdlane(float v, int k) {
    return __int_as_float(__builtin_amdgcn_readlane(__float_as_int(v), k));
}

__device__ inline float wredmax(float v) {
#pragma unroll
    for (int o = 32; o; o >>= 1) v = fmaxf(v, __shfl_xor(v, o));
    return v;
}
__device__ inline float wredmin(float v) {
#pragma unroll
    for (int o = 32; o; o >>= 1) v = fminf(v, __shfl_xor(v, o));
    return v;
}
__device__ inline float wredsum(float v) {
#pragma unroll
    for (int o = 32; o; o >>= 1) v += __shfl_xor(v, o);
    return v;
}

// One block per (batch, feature): 512 threads.
//   half A (tid 0..255): setup, scan, core + lead edge, stage 2.
//   half B (tid 256..511): trailing edge for the same i = tid-256.
// Fused stage 3: last block (atomic counter, no fences) computes final outputs.
__global__ __launch_bounds__(512, 4) void fused_kernel(
    const float* __restrict__ x, const float* __restrict__ t1,
    const float* __restrict__ t2, const float* __restrict__ a,
    const float* __restrict__ b, const float* __restrict__ p,
    const float* __restrict__ tvt, const float* __restrict__ tvl_in,
    float* __restrict__ r1_out, unsigned* __restrict__ counter,
    float* __restrict__ out)
{
    const int bf   = blockIdx.x;      // = bb*NFEAT + f
    const int bb   = bf >> 4;
    const int f    = bf & 15;
    const int tid  = threadIdx.x;
    const int half = tid >> 8;        // 0 = A, 1 = B
    const int i    = tid & 255;
    const int wave = tid >> 6;
    const int lane = tid & 63;

    __shared__ float4 PQ[256];        // (E, E*blv, Em, Em*blv)
    __shared__ float4 PS[257];        // exclusive prefix sums of PQ
    __shared__ float  wpad[320];      // w1+eps at [16+j]; zeros outside j in [0,255]
    __shared__ float4 part4[256];     // B-half partials; reused as sr1 for stage 3
    __shared__ float4 wt4[4];         // scan wave totals; reused for stage-2 sums
    __shared__ float  redA[4], redB[4];
    __shared__ int    lastFlag;

    // ---- window-1 bounds (block-uniform) ----
    float t2h = fminf(fmaxf(t2[f], 0.f), 255.f);
    float t1h = fminf(fmaxf(t1[f], 0.f), 255.f);
    t1h = (t1h >= t2h - 1.f) ? (t2h - 1.f) : t1h;
    const int it1 = (int)t1h, it2 = (int)t2h;
    const int jL  = it1 - 16;                 // lead:  [jL, jL+24)
    const int jT  = max(it2 - 6, it1 + 8);    // trail: [jT, jT+24)
    // core: [it1+8, jT-1] (may be empty)

    float blv = 0.f, lw2 = 0.f, tv0 = 0.f;
    if (half == 0) {
        const float v = a[f] * x[(bb * TLEN + i) * 2] - b[f];
        blv = LB * v;
        const float wm = wredmax(v), wn = wredmin(v);
        if (lane == 0) { redA[wave] = wm; redB[wave] = wn; }
        const float jj = (float)i;
        const float w1 = sigm(BETA * (jj - t1h)) * sigm(BETA * (t2h - jj));
        wpad[16 + i] = w1 + EPSW;
        // hoisted stage-2 params (off the post-loop critical path)
        float t2h2 = fminf(fmaxf(t2[NFEAT + f], 0.f), 255.f);
        float t1h2 = fminf(fmaxf(t1[NFEAT + f], 0.f), 255.f);
        t1h2 = (t1h2 >= t2h2 - 1.f) ? (t2h2 - 1.f) : t1h2;
        const float w2 = sigm(BETA * (jj - t1h2)) * sigm(BETA * (t2h2 - jj));
        lw2 = __logf(w2 + EPSW);
        tv0 = clamp01(tvt[f]);
    } else {
        if (i < 16) wpad[i] = 0.f;
        else if (i < 64) wpad[256 + i] = 0.f;   // indices 272..319
    }
    __syncthreads();  // S1

    const float vmax = fmaxf(fmaxf(redA[0], redA[1]), fmaxf(redA[2], redA[3]));
    const float vmin = fminf(fminf(redB[0], redB[1]), fminf(redB[2], redB[3]));

    float4 sc = make_float4(0.f, 0.f, 0.f, 0.f);
    if (half == 0) {
        const float Ep = EXP2(blv - LB * vmax);
        const float Em = EXP2(LB * vmin - blv);
        const float4 q = make_float4(Ep, Ep * blv, Em, Em * blv);
        PQ[i] = q;
        sc = q;
#pragma unroll
        for (int off = 1; off < 64; off <<= 1) {
            const float ox = __shfl_up(sc.x, off), oy = __shfl_up(sc.y, off);
            const float oz = __shfl_up(sc.z, off), ow = __shfl_up(sc.w, off);
            if (lane >= off) { sc.x += ox; sc.y += oy; sc.z += oz; sc.w += ow; }
        }
        if (lane == 63) wt4[wave] = sc;
    }
    __syncthreads();  // S2

    if (half == 0) {
        float ax = 0.f, ay = 0.f, az = 0.f, aw = 0.f;
        for (int w = 0; w < wave; ++w) {
            const float4 t = wt4[w];
            ax += t.x; ay += t.y; az += t.z; aw += t.w;
        }
        PS[i + 1] = make_float4(sc.x + ax, sc.y + ay, sc.z + az, sc.w + aw);
        if (tid == 0) PS[0] = make_float4(0.f, 0.f, 0.f, 0.f);
    }
    __syncthreads();  // S3

    // ---- stage 1 main work ----
    float sp = 0.f, np = 0.f, sm = 0.f, nm = 0.f;
    if (half == 0) {
        // core via prefix difference + exact clamp count (w == 1 region)
        const int lo = i + it1 + 8;
        const int hi = i + jT - 1;
        const float4 psh = PS[min(hi + 1, 256)];
        const float4 psl = PS[min(lo, 256)];
        const float4 pqe = PQ[255];
        const float  cf  = (float)(max(0, hi - 255) - max(0, lo - 256));
        sp = psh.x - psl.x + cf * pqe.x;
        np = psh.y - psl.y + cf * pqe.y;
        sm = psh.z - psl.z + cf * pqe.z;
        nm = psh.w - psl.w + cf * pqe.w;
        // lead edge, fixed 24 trips; weights via readlane (VALU) not LDS
        const float wlA = wpad[16 + jL + lane];
#pragma unroll
        for (int k = 0; k < 24; ++k) {
            const float wj = rdlane(wlA, k);
            const int t = min(max(i + jL + k, 0), 255);
            const float4 pq = PQ[t];
            sp = fmaf(wj, pq.x, sp); np = fmaf(wj, pq.y, np);
            sm = fmaf(wj, pq.z, sm); nm = fmaf(wj, pq.w, nm);
        }
    } else {
        // trailing edge, fixed 24 trips
        const float wlB = wpad[min(16 + jT + lane, 319)];
#pragma unroll
        for (int k = 0; k < 24; ++k) {
            const float wj = rdlane(wlB, k);
            const int t = min(i + jT + k, 255);
            const float4 pq = PQ[t];
            sp = fmaf(wj, pq.x, sp); np = fmaf(wj, pq.y, np);
            sm = fmaf(wj, pq.z, sm); nm = fmaf(wj, pq.w, nm);
        }
        part4[i] = make_float4(sp, np, sm, nm);
    }
    __syncthreads();  // S4

    // ---- combine halves; stage-2 value y per i ----
    float y = 0.f;
    if (half == 0) {
        const float4 pb = part4[i];
        sp += pb.x; np += pb.y; sm += pb.z; nm += pb.w;
        const float F1 = np / sp, G1 = nm / sm;   // in blv units
        y = (tv0 * F1 + (1.f - tv0) * G1) * (1.f / LB);
        const float ym = wredmax(y), yn = wredmin(y);
        if (lane == 0) { redA[wave] = ym; redB[wave] = yn; }
    }
    __syncthreads();  // S5

    if (half == 0) {
        const float ymax = fmaxf(fmaxf(redA[0], redA[1]), fmaxf(redA[2], redA[3]));
        const float ymin = fminf(fminf(redB[0], redB[1]), fminf(redB[2], redB[3]));
        const float ep2 = EXP2(fmaf(LB, y - ymax, L2E * lw2));
        const float em2 = EXP2(fmaf(LB, ymin - y, L2E * lw2));
        float4 c;
        c.x = wredsum(ep2); c.y = wredsum(ep2 * y);
        c.z = wredsum(em2); c.w = wredsum(em2 * y);
        if (lane == 0) wt4[wave] = c;    // wt4 free since S3
    }
    __syncthreads();  // S6

    if (tid == 0) {
        const float4 s0 = wt4[0], s1 = wt4[1], s2 = wt4[2], s3 = wt4[3];
        const float SP2 = s0.x + s1.x + s2.x + s3.x;
        const float NP2 = s0.y + s1.y + s2.y + s3.y;
        const float SM2 = s0.z + s1.z + s2.z + s3.z;
        const float NM2 = s0.w + s1.w + s2.w + s3.w;
        const float F2 = NP2 / SP2, G2 = NM2 / SM2;
        const float tv1 = clamp01(tvt[NFEAT + f]);
        const float rv  = tv1 * F2 + (1.f - tv1) * G2;
        // device-scope RMW: performed at the coherence point (bypasses XCD L2).
        const float oldv = atomicExch(&r1_out[bf], rv);
        // consume return value -> hw vmcnt drain; memory clobber -> compiler order.
        __asm__ volatile("" :: "v"(oldv) : "memory");
        const unsigned oldc = atomicAdd(counter, 1u);   // mod-512: no init needed
        lastFlag = ((oldc & 511u) == 511u) ? 1 : 0;
    }
    __syncthreads();  // S7

    // ---- fused stage 3: triggered block computes final outputs ----
    if (lastFlag) {
        float* sr1 = (float*)part4;    // 1024 floats of LDS, free now
        {
            const unsigned bits = atomicOr((unsigned*)r1_out + tid, 0u);  // RMW load
            sr1[tid] = __uint_as_float(bits);
        }
        __syncthreads();  // S8

        const float tvl = clamp01(tvl_in[0]);
        if (tid < NBATCH) {
            float vv[NFEAT], lwp[NFEAT];
            float mp = -1e30f, mm = -1e30f;
#pragma unroll
            for (int ff = 0; ff < NFEAT; ++ff) {
                const float pc = clamp01(p[ff]);
                const float lwf = __logf(pc + EPSW);
                const float v = sr1[tid * NFEAT + ff];
                vv[ff] = v; lwp[ff] = lwf;
                mp = fmaxf(mp, fmaf(BETA, v, lwf));
                mm = fmaxf(mm, fmaf(-BETA, v, lwf));
            }
            float sp3 = 0.f, np3 = 0.f, sm3 = 0.f, nm3 = 0.f;
#pragma unroll
            for (int ff = 0; ff < NFEAT; ++ff) {
                const float ep = __expf(fmaf(BETA, vv[ff], lwp[ff]) - mp);
                sp3 += ep; np3 = fmaf(ep, vv[ff], np3);
                const float em = __expf(fmaf(-BETA, vv[ff], lwp[ff]) - mm);
                sm3 += em; nm3 = fmaf(em, vv[ff], nm3);
            }
            out[tid] = tvl * (np3 / sp3) + (1.f - tvl) * (nm3 / sm3);
        }
        if (tid == NBATCH) {
            float bi = 0.f, l2 = 0.f;
#pragma unroll
            for (int k = 0; k < 2 * NFEAT; ++k) {
                const float t = clamp01(tvt[k]);
                bi += t * (1.f - t);
            }
            bi += tvl * (1.f - tvl);
#pragma unroll
            for (int ff = 0; ff < NFEAT; ++ff) {
                const float pc = clamp01(p[ff]);
                bi += pc * (1.f - pc);
                l2 = fmaf(pc, pc, l2);
            }
            out[NBATCH] = W_BI * bi + W_L2 * l2;
        }
    }
}

extern "C" void kernel_launch(void* const* d_in, const int* in_sizes, int n_in,
                              void* d_out, int out_size, void* d_ws, size_t ws_size,
                              hipStream_t stream)
{
    const float* x   = (const float*)d_in[0];
    const float* t1  = (const float*)d_in[1];
    const float* t2  = (const float*)d_in[2];
    const float* a   = (const float*)d_in[3];
    const float* b   = (const float*)d_in[4];
    const float* p   = (const float*)d_in[5];
    const float* tvt = (const float*)d_in[6];
    const float* tvl = (const float*)d_in[7];
    float* out = (float*)d_out;
    float* r1  = (float*)d_ws;                            // 512 floats
    unsigned* counter = (unsigned*)((char*)d_ws + 4096);  // 1 uint (any init value OK)

    fused_kernel<<<NBATCH * NFEAT, 512, 0, stream>>>(
        x, t1, t2, a, b, p, tvt, tvl, r1, counter, out);
}

// Round 8
// 12.017 us; speedup vs baseline: 1.3556x; 1.3556x over previous
//
#include <hip/hip_runtime.h>
#include <math.h>

#define TLEN   256
#define NFEAT  16
#define NBATCH 32
#define BETA   2.5f
#define EPSW   1e-12f
#define W_BI   0.05f
#define W_L2   0.01f
#define L2E    1.4426950408889634f
#define LB     (BETA * L2E)

#if __has_builtin(__builtin_amdgcn_exp2f)
#define EXP2(x) __builtin_amdgcn_exp2f(x)
#else
#define EXP2(x) exp2f(x)
#endif

__device__ inline float sigm(float v) { return 1.f / (1.f + __expf(-v)); }
__device__ inline float clamp01(float v) { return fminf(fmaxf(v, 0.f), 1.f); }
__device__ inline float rdlane(float v, int k) {
    return __int_as_float(__builtin_amdgcn_readlane(__float_as_int(v), k));
}
__device__ inline float wredsum(float v) {
#pragma unroll
    for (int o = 32; o; o >>= 1) v += __shfl_xor(v, o);
    return v;
}

// One block per (batch, feature): 512 threads.
// Unshifted softmax (inputs bounded: |beta*v| <= ~15, safe in f32) =>
// no block max/min reductions anywhere; 3 barriers total.
//   half A (tid 0..255): x load, exp, scan, PS, lead edge, core, stage 2.
//   half B (tid 256..511): window weights, stage-2 log-weights, trail edge.
__global__ __launch_bounds__(512, 4) void stage12_kernel(
    const float* __restrict__ x, const float* __restrict__ t1,
    const float* __restrict__ t2, const float* __restrict__ a,
    const float* __restrict__ b, const float* __restrict__ tvt,
    float* __restrict__ r1_out)
{
    const int bf   = blockIdx.x;      // = bb*NFEAT + f
    const int bb   = bf >> 4;
    const int f    = bf & 15;
    const int tid  = threadIdx.x;
    const int half = tid >> 8;        // 0 = A, 1 = B
    const int i    = tid & 255;
    const int wave = tid >> 6;        // 0..7
    const int lane = tid & 63;

    __shared__ float4 PQ[256];        // (Ep, Ep*blv, Em, Em*blv), unshifted
    __shared__ float4 PS[257];        // exclusive prefix sums of PQ
    __shared__ float  wpad[320];      // w1+eps at [16+j] for j in [0,255]; 0 outside
    __shared__ float4 part4[256];     // B-half trail partials
    __shared__ float4 wt4[4];         // scan wave totals; reused for stage-2 sums
    __shared__ float  lw2s[256];      // stage-2 log-weights

    // ---- window-1 bounds (block-uniform) ----
    float t2h = fminf(fmaxf(t2[f], 0.f), 255.f);
    float t1h = fminf(fmaxf(t1[f], 0.f), 255.f);
    t1h = (t1h >= t2h - 1.f) ? (t2h - 1.f) : t1h;
    const int it1 = (int)t1h, it2 = (int)t2h;
    const int jL  = it1 - 10;                 // lead:  [jL, jL+16)
    const int jT  = max(it2 - 5, it1 + 6);    // trail: [jT, jT+16)
    // core: [it1+6, jT-1] (empty when jT == it1+6)

    float4 sc = make_float4(0.f, 0.f, 0.f, 0.f);
    if (half == 0) {
        const float v   = a[f] * x[(bb * TLEN + i) * 2] - b[f];
        const float blv = LB * v;
        const float Ep  = EXP2(blv);
        const float Em  = EXP2(-blv);
        const float4 q  = make_float4(Ep, Ep * blv, Em, Em * blv);
        PQ[i] = q;
        sc = q;
#pragma unroll
        for (int off = 1; off < 64; off <<= 1) {
            const float ox = __shfl_up(sc.x, off), oy = __shfl_up(sc.y, off);
            const float oz = __shfl_up(sc.z, off), ow = __shfl_up(sc.w, off);
            if (lane >= off) { sc.x += ox; sc.y += oy; sc.z += oz; sc.w += ow; }
        }
        if (lane == 63) wt4[wave] = sc;
    } else {
        // window-1 weights (full padded array)
        {
            const float jj = (float)(i - 16);
            wpad[i] = (i >= 16) ? sigm(BETA * (jj - t1h)) * sigm(BETA * (t2h - jj)) + EPSW
                                : 0.f;
        }
        if (i < 64) {
            const int m = 256 + i;
            const float jj = (float)(m - 16);
            wpad[m] = (m < 16 + TLEN) ? sigm(BETA * (jj - t1h)) * sigm(BETA * (t2h - jj)) + EPSW
                                      : 0.f;
        }
        // stage-2 log-weights
        float t2h2 = fminf(fmaxf(t2[NFEAT + f], 0.f), 255.f);
        float t1h2 = fminf(fmaxf(t1[NFEAT + f], 0.f), 255.f);
        t1h2 = (t1h2 >= t2h2 - 1.f) ? (t2h2 - 1.f) : t1h2;
        const float jj = (float)i;
        const float w2 = sigm(BETA * (jj - t1h2)) * sigm(BETA * (t2h2 - jj));
        lw2s[i] = __logf(w2 + EPSW);
    }
    __syncthreads();  // S1: PQ, wt4, wpad, lw2s ready

    float sp = 0.f, np = 0.f, sm = 0.f, nm = 0.f;
    if (half == 0) {
        // cross-wave scan offsets -> exclusive prefix sums
        float ax = 0.f, ay = 0.f, az = 0.f, aw = 0.f;
        for (int w = 0; w < wave; ++w) {
            const float4 t = wt4[w];
            ax += t.x; ay += t.y; az += t.z; aw += t.w;
        }
        PS[i + 1] = make_float4(sc.x + ax, sc.y + ay, sc.z + az, sc.w + aw);
        if (tid == 0) PS[0] = make_float4(0.f, 0.f, 0.f, 0.f);
        // lead edge, 16 trips; weights via readlane (off the LDS pipe)
        const float wlA = wpad[min(16 + jL + lane, 319)];
#pragma unroll
        for (int k = 0; k < 16; ++k) {
            const float wj = rdlane(wlA, k);
            const int t = min(max(i + jL + k, 0), 255);
            const float4 pq = PQ[t];
            sp = fmaf(wj, pq.x, sp); np = fmaf(wj, pq.y, np);
            sm = fmaf(wj, pq.z, sm); nm = fmaf(wj, pq.w, nm);
        }
    } else {
        // trail edge, 16 trips
        const float wlB = wpad[min(16 + jT + lane, 319)];
#pragma unroll
        for (int k = 0; k < 16; ++k) {
            const float wj = rdlane(wlB, k);
            const int t = min(i + jT + k, 255);
            const float4 pq = PQ[t];
            sp = fmaf(wj, pq.x, sp); np = fmaf(wj, pq.y, np);
            sm = fmaf(wj, pq.z, sm); nm = fmaf(wj, pq.w, nm);
        }
        part4[i] = make_float4(sp, np, sm, nm);
    }
    __syncthreads();  // S2: PS + part4 ready

    if (half == 0) {
        // core via prefix difference + exact clamp count (w == 1 region)
        const int lo = i + it1 + 6;
        const int hi = i + jT - 1;
        const float4 psh = PS[min(hi + 1, 256)];
        const float4 psl = PS[min(lo, 256)];
        const float4 pqe = PQ[255];
        const float  cf  = (float)(max(0, hi - 255) - max(0, lo - 256));
        sp += psh.x - psl.x + cf * pqe.x;
        np += psh.y - psl.y + cf * pqe.y;
        sm += psh.z - psl.z + cf * pqe.z;
        nm += psh.w - psl.w + cf * pqe.w;
        // combine with trail partials
        const float4 pb = part4[i];
        sp += pb.x; np += pb.y; sm += pb.z; nm += pb.w;

        const float F1 = np / sp, G1 = nm / sm;   // in blv units
        const float tv0 = clamp01(tvt[f]);
        const float y = (tv0 * F1 + (1.f - tv0) * G1) * (1.f / LB);

        // stage 2 (unshifted, weighted)
        const float lw2 = lw2s[i];
        const float ep2 = EXP2(fmaf(LB, y, L2E * lw2));
        const float em2 = EXP2(fmaf(-LB, y, L2E * lw2));
        float4 c;
        c.x = wredsum(ep2); c.y = wredsum(ep2 * y);
        c.z = wredsum(em2); c.w = wredsum(em2 * y);
        if (lane == 0) wt4[wave] = c;    // wt4 free since S2
    }
    __syncthreads();  // S3

    if (tid == 0) {
        const float4 s0 = wt4[0], s1 = wt4[1], s2 = wt4[2], s3 = wt4[3];
        const float SP2 = s0.x + s1.x + s2.x + s3.x;
        const float NP2 = s0.y + s1.y + s2.y + s3.y;
        const float SM2 = s0.z + s1.z + s2.z + s3.z;
        const float NM2 = s0.w + s1.w + s2.w + s3.w;
        const float F2 = NP2 / SP2, G2 = NM2 / SM2;
        const float tv1 = clamp01(tvt[NFEAT + f]);
        r1_out[bf] = tv1 * F2 + (1.f - tv1) * G2;
    }
}

// One small block: stage-3 logical soft max/min over features + penalty scalar.
// Unshifted (args bounded), float4 r1 loads.
__global__ __launch_bounds__(64) void stage3_kernel(
    const float* __restrict__ r1, const float* __restrict__ p,
    const float* __restrict__ tvt, const float* __restrict__ tvl_in,
    float* __restrict__ out)
{
    const int tid = threadIdx.x;
    const float tvl = clamp01(tvl_in[0]);

    if (tid < NBATCH) {
        const float4* r4 = (const float4*)(r1 + tid * NFEAT);
        float sp = 0.f, np = 0.f, sm = 0.f, nm = 0.f;
#pragma unroll
        for (int q = 0; q < 4; ++q) {
            const float4 v4 = r4[q];
            const float vs[4] = {v4.x, v4.y, v4.z, v4.w};
#pragma unroll
            for (int c = 0; c < 4; ++c) {
                const int ff = q * 4 + c;
                const float pc  = clamp01(p[ff]);
                const float lwf = L2E * __logf(pc + EPSW);
                const float v   = vs[c];
                const float ep  = EXP2(fmaf(LB, v, lwf));
                const float em  = EXP2(fmaf(-LB, v, lwf));
                sp += ep; np = fmaf(ep, v, np);
                sm += em; nm = fmaf(em, v, nm);
            }
        }
        out[tid] = tvl * (np / sp) + (1.f - tvl) * (nm / sm);
    }

    if (tid == NBATCH) {
        float bi = 0.f, l2 = 0.f;
#pragma unroll
        for (int k = 0; k < 2 * NFEAT; ++k) {
            const float t = clamp01(tvt[k]);
            bi += t * (1.f - t);
        }
        bi += tvl * (1.f - tvl);
#pragma unroll
        for (int ff = 0; ff < NFEAT; ++ff) {
            const float pc = clamp01(p[ff]);
            bi += pc * (1.f - pc);
            l2 = fmaf(pc, pc, l2);
        }
        out[NBATCH] = W_BI * bi + W_L2 * l2;
    }
}

extern "C" void kernel_launch(void* const* d_in, const int* in_sizes, int n_in,
                              void* d_out, int out_size, void* d_ws, size_t ws_size,
                              hipStream_t stream)
{
    const float* x   = (const float*)d_in[0];
    const float* t1  = (const float*)d_in[1];
    const float* t2  = (const float*)d_in[2];
    const float* a   = (const float*)d_in[3];
    const float* b   = (const float*)d_in[4];
    const float* p   = (const float*)d_in[5];
    const float* tvt = (const float*)d_in[6];
    const float* tvl = (const float*)d_in[7];
    float* out = (float*)d_out;
    float* r1  = (float*)d_ws;   // 512 floats scratch

    stage12_kernel<<<NBATCH * NFEAT, 512, 0, stream>>>(x, t1, t2, a, b, tvt, r1);
    stage3_kernel<<<1, 64, 0, stream>>>(r1, p, tvt, tvl, out);
}